// Round 1
// 1571.412 us; speedup vs baseline: 1.0225x; 1.0225x over previous
//
#include <hip/hip_runtime.h>

typedef unsigned long long ull;
typedef __bf16 bf16x8 __attribute__((ext_vector_type(8)));
typedef float f32x4 __attribute__((ext_vector_type(4)));

__device__ __forceinline__ float bf2f(unsigned short u) {
  union { unsigned int i; float f; } c; c.i = ((unsigned int)u) << 16; return c.f;
}
__device__ __forceinline__ unsigned short f2bf(float f) {
  union { float f; unsigned int i; } c; c.f = f;
  unsigned int u = c.i;
  u += 0x7fffu + ((u >> 16) & 1u);
  return (unsigned short)(u >> 16);
}

// ---- pack 4x [256,K] fp32 weights -> bf16 [1024,K] + bias concat ----------
__global__ __launch_bounds__(256) void pack_weights(
    const float* __restrict__ wq, const float* __restrict__ wk,
    const float* __restrict__ wv, const float* __restrict__ ws,
    const float* __restrict__ bq, const float* __restrict__ bk,
    const float* __restrict__ bv, const float* __restrict__ bs,
    unsigned short* __restrict__ Wcat, float* __restrict__ bcat, int logK) {
  int idx = blockIdx.x * 256 + threadIdx.x;
  if (idx < 1024) {
    int rr = idx >> 8, cc = idx & 255;
    const float* bp = (rr == 0) ? bq : (rr == 1) ? bk : (rr == 2) ? bv : bs;
    bcat[idx] = bp[cc];
  }
  int K = 1 << logK;
  if (idx >= (1024 << logK)) return;
  int o = idx >> logK, k = idx & (K - 1);
  int rr = o >> 8, oo = o & 255;
  const float* wp = (rr == 0) ? wq : (rr == 1) ? wk : (rr == 2) ? wv : ws;
  Wcat[idx] = f2bf(wp[oo * K + k]);
}

// ---- embedding gather: x[n, f*64+j] = emb[x_idx[n,f], j], fp32 -> bf16 ----
__global__ __launch_bounds__(256) void embed_gather(
    const int* __restrict__ x_idx, const float* __restrict__ emb,
    unsigned short* __restrict__ xbf, int total) {
  int idx = blockIdx.x * 256 + threadIdx.x;
  if (idx >= total) return;
  int node = idx >> 9, d = idx & 511, f = d >> 6, j = d & 63;
  int vi = x_idx[node * 8 + f];
  xbf[idx] = f2bf(emb[vi * 64 + j]);
}

// ---- CSR build ------------------------------------------------------------
__global__ __launch_bounds__(256) void count_dst(const int* __restrict__ dst,
                                                 int* __restrict__ counts, int E_) {
  int i = blockIdx.x * 256 + threadIdx.x;
  if (i < E_) atomicAdd(&counts[dst[i]], 1);
}

__global__ __launch_bounds__(256) void alloc_rows(const int* __restrict__ counts,
                                                  int* __restrict__ row_start,
                                                  int* __restrict__ cursor,
                                                  int* __restrict__ total, int n) {
  int i = blockIdx.x * 256 + threadIdx.x;
  int lane = threadIdx.x & 63;
  int c = (i < n) ? counts[i] : 0;
  int incl = c;
#pragma unroll
  for (int off = 1; off < 64; off <<= 1) {
    int t = __shfl_up(incl, off, 64);
    if (lane >= off) incl += t;
  }
  int base = 0;
  if (lane == 63) base = atomicAdd(total, incl);
  base = __shfl(base, 63, 64);
  int st = base + incl - c;
  if (i < n) { row_start[i] = st; cursor[i] = st; }
}

// scatter edges into CSR order; materialize permuted src ids and edge attrs
// so the aggregation kernel has NO pointer-chasing and sequential attr reads.
__global__ __launch_bounds__(256) void scatter_edges(
    const int* __restrict__ dst, const int* __restrict__ srcA,
    const float* __restrict__ eattr, int* __restrict__ cursor,
    int* __restrict__ srcs, float* __restrict__ ea_perm, int E_) {
  int i = blockIdx.x * 256 + threadIdx.x;
  if (i >= E_) return;
  int d = dst[i];
  int p = atomicAdd(&cursor[d], 1);
  srcs[p] = srcA[i];
  const float* ea = eattr + (size_t)i * 6;
  float* eo = ea_perm + (size_t)p * 6;
  eo[0] = ea[0]; eo[1] = ea[1]; eo[2] = ea[2];
  eo[3] = ea[3]; eo[4] = ea[4]; eo[5] = ea[5];
}

// ---- fused QKVS GEMM: [N,K]bf16 x [1024,K]bf16 -> q,k,v bf16 + skip fp32 --
// q pre-scaled by 1/16 (1/sqrt(DH)).
template <int K>
__global__ __launch_bounds__(256) void gemm_qkvs(
    const unsigned short* __restrict__ X, const unsigned short* __restrict__ W,
    const float* __restrict__ bcat,
    unsigned short* __restrict__ qout, unsigned short* __restrict__ kout,
    unsigned short* __restrict__ vout, float* __restrict__ sout, int Nn) {
  const int wid = threadIdx.x >> 6;
  const int lane = threadIdx.x & 63;
  const int quad = lane >> 4, lm = lane & 15;
  const int m_base = blockIdx.x * 128 + wid * 32;
  const int n_base = blockIdx.y * 64;
  const int r0 = min(m_base + lm, Nn - 1);
  const int r1 = min(m_base + 16 + lm, Nn - 1);
  const bf16x8* a0p = (const bf16x8*)(X + (size_t)r0 * K + quad * 8);
  const bf16x8* a1p = (const bf16x8*)(X + (size_t)r1 * K + quad * 8);
  const bf16x8* b0p = (const bf16x8*)(W + (size_t)(n_base + lm) * K + quad * 8);
  const bf16x8* b1p = (const bf16x8*)(W + (size_t)(n_base + 16 + lm) * K + quad * 8);
  const bf16x8* b2p = (const bf16x8*)(W + (size_t)(n_base + 32 + lm) * K + quad * 8);
  const bf16x8* b3p = (const bf16x8*)(W + (size_t)(n_base + 48 + lm) * K + quad * 8);
  f32x4 acc[2][4] = {};
#pragma unroll 4
  for (int k0 = 0; k0 < K; k0 += 32) {
    const int ko = k0 >> 3;  // 32 shorts = 4 bf16x8 units
    bf16x8 a0 = a0p[ko], a1 = a1p[ko];
    bf16x8 b0 = b0p[ko], b1 = b1p[ko], b2 = b2p[ko], b3 = b3p[ko];
    acc[0][0] = __builtin_amdgcn_mfma_f32_16x16x32_bf16(a0, b0, acc[0][0], 0, 0, 0);
    acc[0][1] = __builtin_amdgcn_mfma_f32_16x16x32_bf16(a0, b1, acc[0][1], 0, 0, 0);
    acc[0][2] = __builtin_amdgcn_mfma_f32_16x16x32_bf16(a0, b2, acc[0][2], 0, 0, 0);
    acc[0][3] = __builtin_amdgcn_mfma_f32_16x16x32_bf16(a0, b3, acc[0][3], 0, 0, 0);
    acc[1][0] = __builtin_amdgcn_mfma_f32_16x16x32_bf16(a1, b0, acc[1][0], 0, 0, 0);
    acc[1][1] = __builtin_amdgcn_mfma_f32_16x16x32_bf16(a1, b1, acc[1][1], 0, 0, 0);
    acc[1][2] = __builtin_amdgcn_mfma_f32_16x16x32_bf16(a1, b2, acc[1][2], 0, 0, 0);
    acc[1][3] = __builtin_amdgcn_mfma_f32_16x16x32_bf16(a1, b3, acc[1][3], 0, 0, 0);
  }
#pragma unroll
  for (int mi = 0; mi < 2; mi++) {
#pragma unroll
    for (int r = 0; r < 4; r++) {
      int row = m_base + mi * 16 + quad * 4 + r;
      if (row >= Nn) continue;
      size_t rb = (size_t)row * 256;
#pragma unroll
      for (int ni = 0; ni < 4; ni++) {
        int col = n_base + ni * 16 + lm;
        float v = acc[mi][ni][r] + bcat[col];
        int reg = col >> 8, c = col & 255;
        if (reg == 0)       qout[rb + c] = f2bf(v * 0.0625f);
        else if (reg == 1)  kout[rb + c] = f2bf(v);
        else if (reg == 2)  vout[rb + c] = f2bf(v);
        else                sout[rb + c] = v;
      }
    }
  }
}

// edge-feature projection for this lane's 4 dims
__device__ __forceinline__ void edge_e(const float* __restrict__ eab, int ti,
                                       const float (&brow)[4], const float (&wrow)[4][6],
                                       float (&e)[4]) {
  float u0 = eab[ti * 6 + 0], u1 = eab[ti * 6 + 1], u2 = eab[ti * 6 + 2];
  float u3 = eab[ti * 6 + 3], u4 = eab[ti * 6 + 4], u5 = eab[ti * 6 + 5];
#pragma unroll
  for (int r = 0; r < 4; r++)
    e[r] = brow[r] + wrow[r][0] * u0 + wrow[r][1] * u1 + wrow[r][2] * u2
         + wrow[r][3] * u3 + wrow[r][4] * u4 + wrow[r][5] * u5;
}

#define EDGE_DOT(uk, e_)                                                  \
  (q0 * (bf2f((unsigned short)(uk)) + e_[0]) +                            \
   q1 * (bf2f((unsigned short)((uk) >> 16)) + e_[1]) +                    \
   q2 * (bf2f((unsigned short)((uk) >> 32)) + e_[2]) +                    \
   q3 * (bf2f((unsigned short)((uk) >> 48)) + e_[3]))

// ---- per-dst-node edge aggregation with batched online softmax ------------
// one wave per node; lane owns 4 dims (j0 = lane*4).
// Edges processed 4 at a time: all 8 row-gathers issued before any use
// (4x MLP vs serial loop), one softmax rescale per chunk of 4.
// mode 0: write h bf16. mode 1: fused pooling (gap atomicAdd, gmp atomicMax).
__global__ __launch_bounds__(256) void tconv_edges(
    const int* __restrict__ srcs, const float* __restrict__ ea_perm,
    const int* __restrict__ row_start, const int* __restrict__ counts,
    const unsigned short* __restrict__ qv, const unsigned short* __restrict__ kv,
    const unsigned short* __restrict__ vv, const float* __restrict__ skipv,
    const float* __restrict__ we, const float* __restrict__ be,
    int Nn, int mode,
    unsigned short* __restrict__ hout,
    const int* __restrict__ batch, float* __restrict__ gap,
    unsigned int* __restrict__ gmp) {
  __shared__ float we_s[1536];
  __shared__ float be_s[256];
  for (int i = threadIdx.x; i < 1536; i += 256) we_s[i] = we[i];
  be_s[threadIdx.x] = be[threadIdx.x];
  __syncthreads();
  int wid = threadIdx.x >> 6, lane = threadIdx.x & 63;
  int n = blockIdx.x * 4 + wid;
  if (n >= Nn) return;
  int j0 = lane * 4;
  ull uq = *(const ull*)(qv + (size_t)n * 256 + j0);
  float q0 = bf2f((unsigned short)uq), q1 = bf2f((unsigned short)(uq >> 16));
  float q2 = bf2f((unsigned short)(uq >> 32)), q3 = bf2f((unsigned short)(uq >> 48));
  float4 skv = *(const float4*)(skipv + (size_t)n * 256 + j0);
  float brow[4], wrow[4][6];
#pragma unroll
  for (int r = 0; r < 4; r++) {
    brow[r] = be_s[j0 + r];
#pragma unroll
    for (int t = 0; t < 6; t++) wrow[r][t] = we_s[(j0 + r) * 6 + t];
  }
  float m = -INFINITY, ssum = 0.f;
  float a0 = 0.f, a1 = 0.f, a2 = 0.f, a3 = 0.f;
  int beg = row_start[n], cnt = counts[n];
  for (int b0 = 0; b0 < cnt; b0 += 64) {
    int cc = min(cnt - b0, 64);
    int base = beg + b0;
    // one coalesced load: lane i holds src of edge i of this node-chunk
    int srcv = srcs[base + min(lane, cc - 1)];
    const float* eab = ea_perm + (size_t)base * 6;
    for (int c0 = 0; c0 < cc; c0 += 4) {
      int i1 = min(c0 + 1, cc - 1);
      int i2 = min(c0 + 2, cc - 1);
      int i3 = min(c0 + 3, cc - 1);
      int s0 = __shfl(srcv, c0, 64);
      int s1 = __shfl(srcv, i1, 64);
      int s2 = __shfl(srcv, i2, 64);
      int s3 = __shfl(srcv, i3, 64);
      // issue all 8 row gathers before any use
      ull uk0 = *(const ull*)(kv + (size_t)s0 * 256 + j0);
      ull uk1 = *(const ull*)(kv + (size_t)s1 * 256 + j0);
      ull uk2 = *(const ull*)(kv + (size_t)s2 * 256 + j0);
      ull uk3 = *(const ull*)(kv + (size_t)s3 * 256 + j0);
      ull uv0 = *(const ull*)(vv + (size_t)s0 * 256 + j0);
      ull uv1 = *(const ull*)(vv + (size_t)s1 * 256 + j0);
      ull uv2 = *(const ull*)(vv + (size_t)s2 * 256 + j0);
      ull uv3 = *(const ull*)(vv + (size_t)s3 * 256 + j0);
      float e0[4], e1[4], e2[4], e3[4];
      edge_e(eab, c0, brow, wrow, e0);
      edge_e(eab, i1, brow, wrow, e1);
      edge_e(eab, i2, brow, wrow, e2);
      edge_e(eab, i3, brow, wrow, e3);
      float pv0 = EDGE_DOT(uk0, e0);
      float pv1 = EDGE_DOT(uk1, e1);
      float pv2 = EDGE_DOT(uk2, e2);
      float pv3 = EDGE_DOT(uk3, e3);
#pragma unroll
      for (int off = 32; off > 0; off >>= 1) {
        pv0 += __shfl_xor(pv0, off, 64);
        pv1 += __shfl_xor(pv1, off, 64);
        pv2 += __shfl_xor(pv2, off, 64);
        pv3 += __shfl_xor(pv3, off, 64);
      }
      if (c0 + 1 >= cc) pv1 = -INFINITY;  // masked dup edges -> weight 0
      if (c0 + 2 >= cc) pv2 = -INFINITY;
      if (c0 + 3 >= cc) pv3 = -INFINITY;
      float nm = fmaxf(fmaxf(m, fmaxf(pv0, pv1)), fmaxf(pv2, pv3));
      float sc = __expf(m - nm);
      float w0 = __expf(pv0 - nm);
      float w1 = __expf(pv1 - nm);
      float w2 = __expf(pv2 - nm);
      float w3 = __expf(pv3 - nm);
      ssum = ssum * sc + ((w0 + w1) + (w2 + w3));
      a0 = a0 * sc + w0 * (bf2f((unsigned short)uv0) + e0[0])
                   + w1 * (bf2f((unsigned short)uv1) + e1[0])
                   + w2 * (bf2f((unsigned short)uv2) + e2[0])
                   + w3 * (bf2f((unsigned short)uv3) + e3[0]);
      a1 = a1 * sc + w0 * (bf2f((unsigned short)(uv0 >> 16)) + e0[1])
                   + w1 * (bf2f((unsigned short)(uv1 >> 16)) + e1[1])
                   + w2 * (bf2f((unsigned short)(uv2 >> 16)) + e2[1])
                   + w3 * (bf2f((unsigned short)(uv3 >> 16)) + e3[1]);
      a2 = a2 * sc + w0 * (bf2f((unsigned short)(uv0 >> 32)) + e0[2])
                   + w1 * (bf2f((unsigned short)(uv1 >> 32)) + e1[2])
                   + w2 * (bf2f((unsigned short)(uv2 >> 32)) + e2[2])
                   + w3 * (bf2f((unsigned short)(uv3 >> 32)) + e3[2]);
      a3 = a3 * sc + w0 * (bf2f((unsigned short)(uv0 >> 48)) + e0[3])
                   + w1 * (bf2f((unsigned short)(uv1 >> 48)) + e1[3])
                   + w2 * (bf2f((unsigned short)(uv2 >> 48)) + e2[3])
                   + w3 * (bf2f((unsigned short)(uv3 >> 48)) + e3[3]);
      m = nm;
    }
  }
  float inv = (ssum > 0.f) ? 1.f / ssum : 0.f;
  float h0 = fmaxf(a0 * inv + skv.x, 0.f);
  float h1 = fmaxf(a1 * inv + skv.y, 0.f);
  float h2 = fmaxf(a2 * inv + skv.z, 0.f);
  float h3 = fmaxf(a3 * inv + skv.w, 0.f);
  if (mode == 0) {
    ull hv = (ull)f2bf(h0) | ((ull)f2bf(h1) << 16) | ((ull)f2bf(h2) << 32) | ((ull)f2bf(h3) << 48);
    *(ull*)(hout + (size_t)n * 256 + j0) = hv;
  } else {
    int g = batch[n];
    size_t gb = (size_t)g * 256 + j0;
    atomicAdd(&gap[gb + 0], h0); atomicMax(&gmp[gb + 0], __float_as_uint(h0));
    atomicAdd(&gap[gb + 1], h1); atomicMax(&gmp[gb + 1], __float_as_uint(h1));
    atomicAdd(&gap[gb + 2], h2); atomicMax(&gmp[gb + 2], __float_as_uint(h2));
    atomicAdd(&gap[gb + 3], h3); atomicMax(&gmp[gb + 3], __float_as_uint(h3));
  }
}

// ---- per-graph pooling finalize + 3-layer MLP + sigmoid -------------------
__global__ __launch_bounds__(256) void pool_mlp(
    const float* __restrict__ gap, const unsigned int* __restrict__ gmp,
    const int* __restrict__ batch, int Nn,
    const float* __restrict__ w1, const float* __restrict__ b1,
    const float* __restrict__ w2, const float* __restrict__ b2,
    const float* __restrict__ w3, const float* __restrict__ b3,
    float* __restrict__ out) {
  int g = blockIdx.x, t = threadIdx.x;
  __shared__ float r[512];
  __shared__ float o1[256];
  __shared__ float o2[128];
  __shared__ float red[256];
  __shared__ int cnt_s;
  if (t == 0) {
    int lo = 0, hi = Nn;
    while (lo < hi) { int mid = (lo + hi) >> 1; if (batch[mid] < g) lo = mid + 1; else hi = mid; }
    int st = lo;
    lo = 0; hi = Nn;
    while (lo < hi) { int mid = (lo + hi) >> 1; if (batch[mid] < g + 1) lo = mid + 1; else hi = mid; }
    cnt_s = lo - st;
  }
  __syncthreads();
  float inv = 1.f / fmaxf((float)cnt_s, 1.f);
  r[t] = gap[(size_t)g * 256 + t] * inv;
  r[256 + t] = __uint_as_float(gmp[(size_t)g * 256 + t]);
  __syncthreads();
  {
    float a = b1[t];
    const float* wr = w1 + (size_t)t * 512;
    for (int k = 0; k < 512; k++) a += wr[k] * r[k];
    o1[t] = fmaxf(a, 0.f);
  }
  __syncthreads();
  if (t < 128) {
    float a = b2[t];
    const float* wr = w2 + (size_t)t * 256;
    for (int k = 0; k < 256; k++) a += wr[k] * o1[k];
    o2[t] = fmaxf(a, 0.f);
  }
  __syncthreads();
  red[t] = (t < 128) ? w3[t] * o2[t] : 0.f;
  __syncthreads();
  for (int s = 128; s > 0; s >>= 1) {
    if (t < s) red[t] += red[t + s];
    __syncthreads();
  }
  if (t == 0) out[g] = 1.f / (1.f + expf(-(red[0] + b3[0])));
}

// ---------------------------------------------------------------------------
extern "C" void kernel_launch(void* const* d_in, const int* in_sizes, int n_in,
                              void* d_out, int out_size, void* d_ws, size_t ws_size,
                              hipStream_t stream) {
  const int* x_idx      = (const int*)d_in[0];
  const int* edge_index = (const int*)d_in[1];
  const float* eattr    = (const float*)d_in[2];
  const int* batch      = (const int*)d_in[3];
  const float* emb      = (const float*)d_in[4];
  const float* c1_wq = (const float*)d_in[5],  *c1_bq = (const float*)d_in[6];
  const float* c1_wk = (const float*)d_in[7],  *c1_bk = (const float*)d_in[8];
  const float* c1_wv = (const float*)d_in[9],  *c1_bv = (const float*)d_in[10];
  const float* c1_we = (const float*)d_in[11], *c1_be = (const float*)d_in[12];
  const float* c1_ws = (const float*)d_in[13], *c1_bs = (const float*)d_in[14];
  const float* c2_wq = (const float*)d_in[15], *c2_bq = (const float*)d_in[16];
  const float* c2_wk = (const float*)d_in[17], *c2_bk = (const float*)d_in[18];
  const float* c2_wv = (const float*)d_in[19], *c2_bv = (const float*)d_in[20];
  const float* c2_we = (const float*)d_in[21], *c2_be = (const float*)d_in[22];
  const float* c2_ws = (const float*)d_in[23], *c2_bs = (const float*)d_in[24];
  const float* w1 = (const float*)d_in[25], *b1 = (const float*)d_in[26];
  const float* w2 = (const float*)d_in[27], *b2 = (const float*)d_in[28];
  const float* w3 = (const float*)d_in[29], *b3 = (const float*)d_in[30];

  const int Nn = in_sizes[3];        // 50000
  const int Ee = in_sizes[1] / 2;    // 300000

  char* ws = (char*)d_ws;
  size_t off = 0;
  auto alloc = [&](size_t bytes) -> void* {
    void* p = ws + off;
    off += (bytes + 255) & ~(size_t)255;
    return p;
  };
  unsigned short* xbf   = (unsigned short*)alloc((size_t)Nn * 512 * 2);
  unsigned short* qbf   = (unsigned short*)alloc((size_t)Nn * 256 * 2);
  unsigned short* kbf   = (unsigned short*)alloc((size_t)Nn * 256 * 2);
  unsigned short* vbf   = (unsigned short*)alloc((size_t)Nn * 256 * 2);
  float*          skipf = (float*)alloc((size_t)Nn * 256 * 4);
  unsigned short* h1bf  = (unsigned short*)alloc((size_t)Nn * 256 * 2);
  unsigned short* Wcat1 = (unsigned short*)alloc((size_t)1024 * 512 * 2);
  float*          bcat1 = (float*)alloc(1024 * 4);
  unsigned short* Wcat2 = (unsigned short*)alloc((size_t)1024 * 256 * 2);
  float*          bcat2 = (float*)alloc(1024 * 4);
  int*            counts    = (int*)alloc((size_t)Nn * 4);
  int*            row_start = (int*)alloc((size_t)Nn * 4);
  int*            cursor    = (int*)alloc((size_t)Nn * 4);
  int*            srcs      = (int*)alloc((size_t)Ee * 4);
  float*          ea_perm   = (float*)alloc((size_t)Ee * 6 * 4);
  int*            total     = (int*)alloc(256);
  float*          gap       = (float*)alloc((size_t)64 * 256 * 4);
  unsigned int*   gmp       = (unsigned int*)alloc((size_t)64 * 256 * 4);

  const int* srcA = edge_index;
  const int* dstA = edge_index + Ee;

  hipMemsetAsync(counts, 0, (size_t)Nn * 4, stream);
  hipMemsetAsync(total, 0, 4, stream);
  hipMemsetAsync(gap, 0, (size_t)64 * 256 * 4, stream);
  hipMemsetAsync(gmp, 0, (size_t)64 * 256 * 4, stream);

  pack_weights<<<(1024 * 512 + 255) / 256, 256, 0, stream>>>(
      c1_wq, c1_wk, c1_wv, c1_ws, c1_bq, c1_bk, c1_bv, c1_bs, Wcat1, bcat1, 9);
  pack_weights<<<(1024 * 256 + 255) / 256, 256, 0, stream>>>(
      c2_wq, c2_wk, c2_wv, c2_ws, c2_bq, c2_bk, c2_bv, c2_bs, Wcat2, bcat2, 8);
  embed_gather<<<((Nn * 512) + 255) / 256, 256, 0, stream>>>(x_idx, emb, xbf, Nn * 512);
  count_dst<<<(Ee + 255) / 256, 256, 0, stream>>>(dstA, counts, Ee);
  alloc_rows<<<(Nn + 255) / 256, 256, 0, stream>>>(counts, row_start, cursor, total, Nn);
  scatter_edges<<<(Ee + 255) / 256, 256, 0, stream>>>(dstA, srcA, eattr, cursor,
                                                      srcs, ea_perm, Ee);

  dim3 gg((Nn + 127) / 128, 16);
  gemm_qkvs<512><<<gg, 256, 0, stream>>>(xbf, Wcat1, bcat1, qbf, kbf, vbf, skipf, Nn);
  tconv_edges<<<(Nn + 3) / 4, 256, 0, stream>>>(
      srcs, ea_perm, row_start, counts, qbf, kbf, vbf, skipf,
      c1_we, c1_be, Nn, 0, h1bf, nullptr, nullptr, nullptr);
  gemm_qkvs<256><<<gg, 256, 0, stream>>>(h1bf, Wcat2, bcat2, qbf, kbf, vbf, skipf, Nn);
  tconv_edges<<<(Nn + 3) / 4, 256, 0, stream>>>(
      srcs, ea_perm, row_start, counts, qbf, kbf, vbf, skipf,
      c2_we, c2_be, Nn, 1, nullptr, batch, gap, gmp);
  pool_mlp<<<64, 256, 0, stream>>>(gap, gmp, batch, Nn, w1, b1, w2, b2, w3, b3,
                                   (float*)d_out);
}